// Round 1
// baseline (101.062 us; speedup 1.0000x reference)
//
#include <hip/hip_runtime.h>
#include <math.h>

#define FEAS 4096
#define K 64
#define BATCH 4096

typedef float f4 __attribute__((ext_vector_type(4)));

// ws layout (floats): [0..63] col_sum, [64] diag (sum of squares)

__global__ __launch_bounds__(256) void cross_reduce_kernel(
    const float* __restrict__ cross, float* __restrict__ ws) {
    // 64 blocks x 256 threads; block b handles rows [b*64, b*64+64) of V (4096x64)
    const int j     = threadIdx.x & 63;   // column 0..63
    const int rlane = threadIdx.x >> 6;   // 0..3
    const int row0  = blockIdx.x * 64;

    float s = 0.f, q = 0.f;
#pragma unroll
    for (int i = 0; i < 16; ++i) {
        const int r = row0 + rlane + i * 4;
        const float v = cross[r * K + j];
        s += v;
        q += v * v;
    }

    __shared__ float ls[256];
    __shared__ float lq[256];
    ls[threadIdx.x] = s;
    lq[threadIdx.x] = q;
    __syncthreads();

    if (threadIdx.x < 64) {  // wave 0 only
        const float cs = ls[j] + ls[j + 64] + ls[j + 128] + ls[j + 192];
        atomicAdd(&ws[j], cs);

        float cq = lq[j] + lq[j + 64] + lq[j + 128] + lq[j + 192];
#pragma unroll
        for (int off = 32; off; off >>= 1) cq += __shfl_down(cq, off, 64);
        if (j == 0) atomicAdd(&ws[64], cq);
    }
}

// Wave-per-row GEMV: no LDS, no __syncthreads, 16 independent float4 loads
// of x per lane in flight (vs 4 in the block-per-row version).
__global__ __launch_bounds__(256) void gemv_sigmoid_kernel(
    const float* __restrict__ x, const float* __restrict__ w,
    const float* __restrict__ bias, const float* __restrict__ ws,
    float* __restrict__ out) {
    const int lane = threadIdx.x & 63;
    const int row  = blockIdx.x * 4 + (threadIdx.x >> 6);  // 1024 blocks * 4 waves

    // cross_sum + bias, recomputed per wave from ws (65 floats, L2-hot).
    // Butterfly reduce so ALL lanes end up with the value (no LDS needed).
    const float c = ws[lane];
    float t = c * c;
#pragma unroll
    for (int m = 32; m; m >>= 1) t += __shfl_xor(t, m, 64);
    const float add = 0.5f * (t + ws[64]) + bias[0];

    const f4* __restrict__ xr = (const f4*)(x + (size_t)row * FEAS);
    const f4* __restrict__ wv = (const f4*)w;

    float acc = 0.f;
#pragma unroll
    for (int i = 0; i < 16; ++i) {
        const f4 a = xr[i * 64 + lane];  // coalesced: 64 lanes * 16 B = 1 KiB/instr
        const f4 b = wv[i * 64 + lane];  // L1/L2-resident (16 KiB, reused by all waves)
        acc = fmaf(a.x, b.x, fmaf(a.y, b.y, fmaf(a.z, b.z, fmaf(a.w, b.w, acc))));
    }

    // Full-wave butterfly reduce.
#pragma unroll
    for (int m = 32; m; m >>= 1) acc += __shfl_xor(acc, m, 64);

    if (lane == 0) {
        const float y = acc + add;
        out[row] = 1.0f / (1.0f + expf(-y));
    }
}

extern "C" void kernel_launch(void* const* d_in, const int* in_sizes, int n_in,
                              void* d_out, int out_size, void* d_ws, size_t ws_size,
                              hipStream_t stream) {
    const float* x     = (const float*)d_in[0];  // (4096, 4096)
    const float* cross = (const float*)d_in[1];  // (4096, 1, 64)
    const float* w     = (const float*)d_in[2];  // (1, 4096)
    const float* b     = (const float*)d_in[3];  // (1,)
    float* out = (float*)d_out;                  // (4096, 1)
    float* ws  = (float*)d_ws;

    // ws is re-poisoned to 0xAA before every timed launch: zero what we use.
    hipMemsetAsync(ws, 0, 65 * sizeof(float), stream);

    cross_reduce_kernel<<<64, 256, 0, stream>>>(cross, ws);
    gemv_sigmoid_kernel<<<BATCH / 4, 256, 0, stream>>>(x, w, b, ws, out);
}